// Round 4
// baseline (336.673 us; speedup 1.0000x reference)
//
#include <hip/hip_runtime.h>

#define H 8
#define NSEQ 4096
#define DIM 64
#define BATCH 8
#define AREV_LEN 4704   // 4096 lags + 608 zero pad (chain depth 8 x32 + prefetch-2 overrun).
                        // 4704 elems = 2352 dwords == 16 mod 32 -> lds1 (at +AREV_LEN) sits at
                        // bank offset +16 vs lds0: parity groups hit disjoint bank halves.
#define HD (H*DIM)      // 512
#define XP_PAD 256      // B prefetch-2 overrun past last row

typedef __attribute__((ext_vector_type(8))) short short8;
typedef __attribute__((ext_vector_type(4))) float float4v;

__device__ inline unsigned short f32_to_bf16(float f) {
    unsigned int u = __float_as_uint(f);
    u += 0x7fffu + ((u >> 16) & 1u);   // RNE
    return (unsigned short)(u >> 16);
}

// ---- P1: arev[hd][i] = bf16( exp(clamp(log(gamma)*k + pos[k-1])) ) at k = 4095 - i ----
// (k==0 uses `zero`). i in [4096,4704) stays 0 from the memset (negative lags).
__global__ __launch_bounds__(256) void build_arev(
    const float* __restrict__ zero, const float* __restrict__ pos,
    const float* __restrict__ gamma, unsigned short* __restrict__ arev)
{
    __shared__ unsigned short T[64][65];
    int h = blockIdx.y, kb = blockIdx.x;
    int tid = threadIdx.x;
    #pragma unroll
    for (int jj = 0; jj < 16; ++jj) {
        int e = tid + 256*jj;
        int kk = e >> 6, dd = e & 63;
        int k = kb*64 + kk;
        float v;
        if (k == 0) v = zero[h*64 + dd];
        else        v = logf(gamma[h*64 + dd]) * (float)k + pos[(h*4095 + (k-1))*64 + dd];
        v = fminf(30.f, fmaxf(-60.f, v));
        T[kk][dd] = f32_to_bf16(expf(v));
    }
    __syncthreads();
    int i0 = 4032 - kb*64;   // tile writes arev[hd][i0 .. i0+63], i = 4095 - k
    #pragma unroll
    for (int jj = 0; jj < 16; ++jj) {
        int e = tid + 256*jj;
        int dpr = e >> 6, ii = e & 63;
        arev[(size_t)(h*64 + dpr)*AREV_LEN + i0 + ii] = T[63 - ii][dpr];
    }
}

// ---- P2: xp[hd][b][s] = bf16(x[b][h][s][d])  (coalesced LDS transpose) ----
__global__ __launch_bounds__(256) void build_xp(
    const float* __restrict__ x, unsigned short* __restrict__ xp)
{
    __shared__ unsigned short T[64][65];
    int sb = blockIdx.x, h = blockIdx.y, b = blockIdx.z;
    int tid = threadIdx.x;
    const float* src = x + ((size_t)(b*H + h)*NSEQ + sb*64)*DIM;
    #pragma unroll
    for (int jj = 0; jj < 16; ++jj) {
        int e = tid + 256*jj;
        int ss = e >> 6, dd = e & 63;
        T[ss][dd] = f32_to_bf16(src[ss*64 + dd]);
    }
    __syncthreads();
    #pragma unroll
    for (int jj = 0; jj < 16; ++jj) {
        int e = tid + 256*jj;
        int dpr = e >> 6, ii = e & 63;
        xp[((size_t)(h*64 + dpr)*BATCH + b)*NSEQ + sb*64 + ii] = T[ii][dpr];
    }
}

// ---- GEMM: per (h,d): Out[t, 0:8] = sum_s a[t-s] * X[s, 0:8], causal ----
// One WG = one (h,d) and a 512-row t-tile. 4 waves; each wave owns 8 sub-tiles of
// 16 rows spaced 32 apart. Ring-of-16 A-frags (prefetch distance 2) + ring-of-4
// B-frags, unroll-16 inner loop: all ring indices compile-time, all LDS/global
// addresses immediate offsets -> ~zero VALU per iteration.
__global__ __launch_bounds__(256) void toeplitz_gemm(
    const unsigned short* __restrict__ arev,
    const unsigned short* __restrict__ xp,
    float* __restrict__ out)
{
    __shared__ unsigned short lds[2*AREV_LEN];   // [0]: arev, [AREV_LEN]: arev shifted +1

    // swizzle: 16 line-sharing consecutive-d WGs -> same XCD (id%8); big t-tiles first.
    int id = blockIdx.x;                 // [0, 4096)
    int q8 = id >> 7, rem = id & 127;
    int rr_ = rem >> 3, xx = rem & 7;
    int g_  = q8*8 + xx;                 // [0, 256)
    int nlin = g_*16 + rr_;              // [0, 4096)
    int tt = 7 - (nlin >> 9);
    int h  = (nlin >> 6) & 7;
    int d  = nlin & 63;
    int hd = h*64 + d;
    int T0 = tt*512;

    int tid = threadIdx.x;
    const unsigned short* ga = arev + (size_t)hd*AREV_LEN;
    for (int i = tid; i < AREV_LEN; i += 256) lds[i] = ga[i];
    for (int i = tid; i < AREV_LEN-1; i += 256) lds[AREV_LEN + i] = ga[i+1];
    if (tid == 0) lds[2*AREV_LEN - 1] = 0;
    __syncthreads();

    int w = tid >> 6, lane = tid & 63;
    int nb = lane & 15;        // A-frag row m and B-frag col n (batch)
    int q  = lane >> 4;        // k-quad
    int b  = T0 + 16*(w & 1) + 256*(w >> 1);   // wave: t in {b+32j, j<8} + [0,16)

    float4v acc[8];
    #pragma unroll
    for (int j = 0; j < 8; ++j) acc[j] = (float4v){0.f,0.f,0.f,0.f};

    const unsigned short* xrow = xp + ((size_t)hd*BATCH + (nb & 7))*NSEQ;
    const unsigned int* l32_0 = (const unsigned int*)lds;
    const unsigned int* l32_1 = (const unsigned int*)(lds + AREV_LEN);

    int B0  = 4095 - b - nb;
    int i00 = B0 + 8*q;                        // i0 at s0=0; parity loop-invariant
    const unsigned int* ap = ((i00 & 1) ? l32_1 : l32_0) + (i00 >> 1);  // frag_0(32n) @ ap+16n
    const unsigned short* bp = xrow + 8*q;                              // b(32n) @ bp+32n

    // A ring g[16]: at iteration n, sub-tile j reads g[(n-j)&15]; prefetch writes g[(n+2)&15].
    short8 g[16];
    #pragma unroll
    for (int j = 1; j < 8; ++j) {              // g[16-j] = frag_0(-32j) (chain init, in-bounds)
        const unsigned int* p = ap - 16*j;
        union { short8 v; unsigned int u[4]; } af;
        af.u[0] = p[0]; af.u[1] = p[1]; af.u[2] = p[2]; af.u[3] = p[3];
        g[16 - j] = af.v;
    }
    #pragma unroll
    for (int j = 0; j < 2; ++j) {              // g[0]=frag_0(0), g[1]=frag_0(32)
        const unsigned int* p = ap + 16*j;
        union { short8 v; unsigned int u[4]; } af;
        af.u[0] = p[0]; af.u[1] = p[1]; af.u[2] = p[2]; af.u[3] = p[3];
        g[j] = af.v;
    }
    short8 bb[4];
    bb[0] = *reinterpret_cast<const short8*>(bp);
    bb[1] = *reinterpret_cast<const short8*>(bp + 32);

    int nch = tt + 1;                          // 16 iterations per chunk; s_end = T0+512
    #pragma unroll 1
    for (int cc = 0; cc < nch; ++cc) {
        #pragma unroll
        for (int r = 0; r < 16; ++r) {
            {   // prefetch A frag for n+2 (dead slot, imm offsets)
                const unsigned int* p = ap + 16*(r + 2);
                union { short8 v; unsigned int u[4]; } af;
                af.u[0] = p[0]; af.u[1] = p[1]; af.u[2] = p[2]; af.u[3] = p[3];
                g[(r + 2) & 15] = af.v;
            }
            bb[(r + 2) & 3] = *reinterpret_cast<const short8*>(bp + 32*(r + 2));
            short8 bf = bb[r & 3];
            #pragma unroll
            for (int j = 0; j < 8; ++j)
                acc[j] = __builtin_amdgcn_mfma_f32_16x16x32_bf16(g[(r - j) & 15], bf, acc[j], 0, 0, 0);
        }
        ap += 256;   // 16 iters x 16 dwords
        bp += 512;   // 16 iters x 32 elems
    }

    // C/D: col(batch) = lane&15, row(t within 16) = q*4 + rr; sub-tile j at t base b+32j
    if (nb < 8) {
        float* obase = out + ((size_t)(nb*H + h)*NSEQ)*DIM + d;
        #pragma unroll
        for (int j = 0; j < 8; ++j) {
            #pragma unroll
            for (int rr = 0; rr < 4; ++rr) {
                int t = b + 32*j + 4*q + rr;
                obase[(size_t)t*DIM] = acc[j][rr];
            }
        }
    }
}

extern "C" void kernel_launch(void* const* d_in, const int* in_sizes, int n_in,
                              void* d_out, int out_size, void* d_ws, size_t ws_size,
                              hipStream_t stream) {
    const float* x     = (const float*)d_in[0];
    const float* zero  = (const float*)d_in[1];
    const float* pos   = (const float*)d_in[2];
    const float* gamma = (const float*)d_in[3];
    float* out = (float*)d_out;

    unsigned short* arev = (unsigned short*)d_ws;                 // 512*4704*2 = 4.82 MB
    unsigned short* xp   = arev + (size_t)HD*AREV_LEN;            // 512*8*4096*2 + pad = 33.6 MB

    hipMemsetAsync(arev, 0, (size_t)HD*AREV_LEN*sizeof(unsigned short), stream);
    build_arev<<<dim3(64, 8), 256, 0, stream>>>(zero, pos, gamma, arev);
    build_xp<<<dim3(64, 8, 8), 256, 0, stream>>>(x, xp);
    toeplitz_gemm<<<dim3(512*8), 256, 0, stream>>>(arev, xp, out);
}